// Round 9
// baseline (819.678 us; speedup 1.0000x reference)
//
#include <hip/hip_runtime.h>
#include <hip/hip_bf16.h>
#include <math.h>

#define T_TOK 2048
#define H_DIM 2048
#define E_NUM 64
#define F_DIM 512
#define K_TOP 8
#define FS_DIM 512
#define NROWS (T_TOK * K_TOP)

typedef __attribute__((ext_vector_type(8))) short short8v;   // bf16x8 MFMA frag
typedef __attribute__((ext_vector_type(4))) float f32x4;     // MFMA accum

static __device__ __forceinline__ unsigned short f2bf(float f) {
    unsigned int u = __float_as_uint(f);
    u += 0x7fff + ((u >> 16) & 1);           // RNE to bf16
    return (unsigned short)(u >> 16);
}

// 16B-chunk swizzles (row stride = 64 shorts = 128B, bank-neutral)
#define BCHUNK(row, k8) ((((k8) ^ ((row) + ((row) >> 3)))) & 7)
#define ASWZ(row) (((row) + ((row) >> 3)) & 7)

typedef const unsigned int __attribute__((address_space(1))) gu32;
typedef unsigned int __attribute__((address_space(3))) lu32;
// async global->LDS, 16B per lane; dest = wave-uniform base + lane*16
#define GLDS16(gsrc, ldst) \
    __builtin_amdgcn_global_load_lds((gu32*)(gsrc), (lu32*)(ldst), 16, 0, 0)

// ---------------------------------------------------------------------------
// x (fp32) -> bf16 copy, vectorized 8/thread
// ---------------------------------------------------------------------------
__global__ __launch_bounds__(256) void cvt_bf16_kernel(
    const float* __restrict__ in, unsigned short* __restrict__ out, int n8)
{
    int i = blockIdx.x * 256 + threadIdx.x;
    if (i < n8) {
        const float4* p = (const float4*)(in + (size_t)i * 8);
        float4 v0 = p[0], v1 = p[1];
        ushort4 a = make_ushort4(f2bf(v0.x), f2bf(v0.y), f2bf(v0.z), f2bf(v0.w));
        ushort4 b = make_ushort4(f2bf(v1.x), f2bf(v1.y), f2bf(v1.z), f2bf(v1.w));
        ushort4* q = (ushort4*)(out + (size_t)i * 8);
        q[0] = a; q[1] = b;
    }
}

// ---------------------------------------------------------------------------
// Router: one wave per token (fp32 math, exact top-k vs reference).
// ---------------------------------------------------------------------------
__global__ __launch_bounds__(64) void router_kernel(
    const float* __restrict__ x, const float* __restrict__ Wg,
    int* __restrict__ topk_idx, float* __restrict__ topk_w,
    float* __restrict__ sgate, int* __restrict__ counts)
{
    const int t = blockIdx.x;
    const int lane = threadIdx.x;
    const float* xr = x + (size_t)t * H_DIM;

    float a0 = 0.f, a1 = 0.f, a2 = 0.f, a3 = 0.f;
    for (int h = 0; h < H_DIM; h += 4) {
        float4 xv = *(const float4*)&xr[h];
        a0 += xv.x * Wg[(h + 0) * 65 + lane];
        a1 += xv.y * Wg[(h + 1) * 65 + lane];
        a2 += xv.z * Wg[(h + 2) * 65 + lane];
        a3 += xv.w * Wg[(h + 3) * 65 + lane];
    }
    float logit = (a0 + a1) + (a2 + a3);

    float a64 = 0.f;
    for (int h = lane; h < H_DIM; h += 64) a64 += xr[h] * Wg[h * 65 + 64];
#pragma unroll
    for (int off = 32; off >= 1; off >>= 1) a64 += __shfl_xor(a64, off);

    float v = logit;
    float selv[K_TOP]; int seli[K_TOP];
#pragma unroll
    for (int k = 0; k < K_TOP; ++k) {
        float mv = v; int mi = lane;
#pragma unroll
        for (int off = 32; off >= 1; off >>= 1) {
            float ov = __shfl_xor(mv, off);
            int   oi = __shfl_xor(mi, off);
            if (ov > mv || (ov == mv && oi < mi)) { mv = ov; mi = oi; }
        }
        selv[k] = mv; seli[k] = mi;
        if (lane == mi) v = -INFINITY;
    }

    if (lane == 0) {
        float m = selv[0];
        float w[K_TOP]; float s = 0.f;
#pragma unroll
        for (int k = 0; k < K_TOP; ++k) { w[k] = __expf(selv[k] - m); s += w[k]; }
        float inv = 1.f / s;
#pragma unroll
        for (int k = 0; k < K_TOP; ++k) {
            topk_idx[t * K_TOP + k] = seli[k];
            topk_w[t * K_TOP + k] = w[k] * inv;
            atomicAdd(&counts[seli[k]], 1);
        }
        sgate[t] = 1.f / (1.f + __expf(-a64));
    }
}

// ---------------------------------------------------------------------------
// Deterministic per-expert compaction.
// ---------------------------------------------------------------------------
__global__ __launch_bounds__(256) void bucket_kernel(
    const int* __restrict__ topk_idx, const float* __restrict__ topk_w,
    const int* __restrict__ counts, int* __restrict__ offsets,
    int* __restrict__ bucket_tok, float* __restrict__ bucket_w)
{
    const int e = blockIdx.x, thr = threadIdx.x;
    __shared__ int cnt[256];
    __shared__ int base_s;
    const int q0 = thr * 64;
    int c = 0;
    for (int q = 0; q < 64; ++q) c += (topk_idx[q0 + q] == e) ? 1 : 0;
    cnt[thr] = c;
    __syncthreads();
    if (thr == 0) {
        int off = 0;
        for (int i = 0; i < e; ++i) off += counts[i];
        offsets[e] = off;
        base_s = off;
        int run = 0;
        for (int i = 0; i < 256; ++i) { int tval = cnt[i]; cnt[i] = run; run += tval; }
    }
    __syncthreads();
    int pos = base_s + cnt[thr];
    for (int q = 0; q < 64; ++q) {
        int pp = q0 + q;
        if (topk_idx[pp] == e) {
            bucket_tok[pos] = pp >> 3;
            bucket_w[pos] = topk_w[pp];
            ++pos;
        }
    }
}

// ---------------------------------------------------------------------------
// gate_up + SiLU*u*topw, m97 2-barrier structure (__syncthreads has full
// vmcnt+lgkm drain semantics — no hand-counted waits). Per K64-step:
//   __syncthreads(); 4x GLDS A(t); ds_write B(t); issue W(t+1);
//   __syncthreads(); ds_read frags; 16 MFMA.
// A staged via global_load_lds: linear LDS dest, inverse-swizzled global src,
// swizzled read (rule #21). W fp32->bf16 reg-transposed into LDS.
// Block 512 thr = 8 waves (4 wm x 2 wn); wave tile 64 rows x 16 act cols.
// ---------------------------------------------------------------------------
template<bool ROUTED>
__global__ __launch_bounds__(512, 6) void gu_mfma_kernel(
    const unsigned short* __restrict__ xb,
    const float* __restrict__ Wall,
    const int* __restrict__ counts, const int* __restrict__ offsets,
    const int* __restrict__ bucket_tok, const float* __restrict__ bucket_w,
    unsigned short* __restrict__ actout)
{
    constexpr int BM = 256;
    __shared__ __align__(16) unsigned short As[BM * 64];   // 32 KB
    __shared__ __align__(16) unsigned short Bs[64 * 64];   // 8 KB
    __shared__ int   toksS[BM];
    __shared__ float twsS[BM];

    const int tid  = threadIdx.x;
    const int lane = tid & 63;
    const int wid  = tid >> 6;
    const int wm = wid >> 1, wn = wid & 1;
    const int lrow = lane & 15, lhi = lane >> 4;

    int cblk, mt, ne, base;
    const float* W;
    if (ROUTED) {
        int nw = (blockIdx.x & 7) * ((int)gridDim.x >> 3) + (blockIdx.x >> 3);
        int e = nw >> 5; mt = (nw >> 4) & 1; cblk = nw & 15;
        ne = counts[e]; base = offsets[e];
        if (mt * BM >= ne) return;                 // overflow tile unused
        W = Wall + (size_t)e * H_DIM * (2 * F_DIM);
    } else {
        cblk = blockIdx.x; mt = blockIdx.y;
        ne = T_TOK; base = 0;
        W = Wall;
    }
    const int c0 = cblk * 32;               // act-col base

    // W staging geometry: thread covers 4 n-cols x 2 k-rows
    const int n4 = (tid & 15) * 4;
    const int kb = (tid >> 4) * 2;
    const int n5 = n4 & 31;
    const int wcol = ((n5 < 16) ? 0 : (F_DIM - 16)) + c0 + (n4 >> 5) * 16 + n5;
    int wr_off[4];
#pragma unroll
    for (int cc = 0; cc < 4; ++cc) {
        int n = n4 + cc;
        wr_off[cc] = n * 64 + BCHUNK(n, kb >> 3) * 8 + (kb & 7);
    }
    // B read offsets (per ks): rows rg (gate), ru (up)
    const int rg = wn * 32 + lrow, ru = wn * 32 + 16 + lrow;
    int rdBg[2], rdBu[2];
#pragma unroll
    for (int ks = 0; ks < 2; ++ks) {
        int kc = ks * 4 + lhi;
        rdBg[ks] = rg * 64 + BCHUNK(rg, kc) * 8;
        rdBu[ks] = ru * 64 + BCHUNK(ru, kc) * 8;
    }
    // A read offsets: rows arow = wm*64 + fm*16 + lrow
    int rdA[4][2];
#pragma unroll
    for (int fm = 0; fm < 4; ++fm) {
        int arow = wm * 64 + fm * 16 + lrow;
#pragma unroll
        for (int ks = 0; ks < 2; ++ks) {
            int kc = ks * 4 + lhi;
            rdA[fm][ks] = arow * 64 + (((kc ^ ASWZ(arow)) & 7) << 3);
        }
    }
    const int m0_stride = ROUTED ? (2 * BM) : ((int)gridDim.y * BM);

    for (int m0 = mt * BM; m0 < ne; m0 += m0_stride) {
        __syncthreads();
        if (tid < BM) {
            int idx = m0 + tid; bool v = idx < ne;
            if (ROUTED) {
                toksS[tid] = v ? bucket_tok[base + idx] : bucket_tok[base];
                twsS[tid]  = v ? bucket_w[base + idx] : 0.f;
            } else {
                toksS[tid] = v ? idx : (T_TOK - 1);
                twsS[tid]  = 1.f;
            }
        }
        __syncthreads();

        // per-lane A-source element offsets (4 staging issues)
        int asrc[4];
#pragma unroll
        for (int i = 0; i < 4; ++i) {
            int row = wid * 32 + i * 8 + (lane >> 3);
            asrc[i] = toksS[row] * H_DIM + (((lane & 7) ^ ASWZ(row)) << 3);
        }

        f32x4 acc[4][2];
#pragma unroll
        for (int i = 0; i < 4; ++i) {
            acc[i][0] = (f32x4){0.f, 0.f, 0.f, 0.f};
            acc[i][1] = (f32x4){0.f, 0.f, 0.f, 0.f};
        }

        const int NT = H_DIM / 64;
        // W(0) into regs
        float4 b0 = *(const float4*)&W[(size_t)kb * (2 * F_DIM) + wcol];
        float4 b1 = *(const float4*)&W[(size_t)(kb + 1) * (2 * F_DIM) + wcol];

        for (int kt = 0; kt < NT; ++kt) {
            const int k0 = kt * 64;
            __syncthreads();                     // readers of tile(kt-1) done
            // A(kt) -> LDS (async, drained by the next __syncthreads)
#pragma unroll
            for (int i = 0; i < 4; ++i)
                GLDS16(xb + asrc[i] + k0, &As[(wid * 32 + i * 8) * 64]);
            // B(kt): regs -> LDS
#pragma unroll
            for (int cc = 0; cc < 4; ++cc)
                *(ushort2*)&Bs[wr_off[cc]] = make_ushort2(
                    f2bf(((const float*)&b0)[cc]), f2bf(((const float*)&b1)[cc]));
            // W(kt+1) (clamped dup at tail)
            {
                int knx = (kt + 1 < NT) ? (k0 + 64) : k0;
                b0 = *(const float4*)&W[(size_t)(knx + kb) * (2 * F_DIM) + wcol];
                b1 = *(const float4*)&W[(size_t)(knx + kb + 1) * (2 * F_DIM) + wcol];
            }
            __syncthreads();                     // full drain: A + B visible
            // compute
#pragma unroll
            for (int ks = 0; ks < 2; ++ks) {
                short8v bg = *(const short8v*)&Bs[rdBg[ks]];
                short8v bu = *(const short8v*)&Bs[rdBu[ks]];
#pragma unroll
                for (int fm = 0; fm < 4; ++fm) {
                    short8v af = *(const short8v*)&As[rdA[fm][ks]];
                    acc[fm][0] = __builtin_amdgcn_mfma_f32_16x16x32_bf16(af, bg, acc[fm][0], 0, 0, 0);
                    acc[fm][1] = __builtin_amdgcn_mfma_f32_16x16x32_bf16(af, bu, acc[fm][1], 0, 0, 0);
                }
            }
        }

        // epilogue: silu(g)*u*topw -> bf16 act
        const int acol = c0 + wn * 16 + lrow;
#pragma unroll
        for (int fm = 0; fm < 4; ++fm) {
#pragma unroll
            for (int i = 0; i < 4; ++i) {
                int ml = wm * 64 + fm * 16 + lhi * 4 + i;
                int idx = m0 + ml;
                if (idx < ne) {
                    float gv = acc[fm][0][i], uv = acc[fm][1][i];
                    float s = gv / (1.f + __expf(-gv));
                    float val = s * uv * twsS[ml];
                    size_t orow = ROUTED ? (size_t)(base + idx) : (size_t)idx;
                    actout[orow * F_DIM + acol] = f2bf(val);
                }
            }
        }
    }
}

// ---------------------------------------------------------------------------
// down-proj, same structure. A = packed act rows (contiguous, no gather).
// ROUTED: atomicAdd scatter to out; shared: plain store * sigmoid.
// ---------------------------------------------------------------------------
template<bool ROUTED>
__global__ __launch_bounds__(512, 6) void down_mfma_kernel(
    const unsigned short* __restrict__ actb,
    const float* __restrict__ Wall,
    const int* __restrict__ counts, const int* __restrict__ offsets,
    const int* __restrict__ bucket_tok, const float* __restrict__ sgate,
    float* __restrict__ out)
{
    constexpr int BM = 256;
    __shared__ __align__(16) unsigned short As[BM * 64];
    __shared__ __align__(16) unsigned short Bs[64 * 64];
    __shared__ int   toksS[BM];
    __shared__ float sgS[BM];

    const int tid  = threadIdx.x;
    const int lane = tid & 63;
    const int wid  = tid >> 6;
    const int wm = wid >> 1, wn = wid & 1;
    const int lrow = lane & 15, lhi = lane >> 4;

    int cblk, mt, ne, base;
    const float* W;
    if (ROUTED) {
        int nw = (blockIdx.x & 7) * ((int)gridDim.x >> 3) + (blockIdx.x >> 3);
        int e = nw >> 6; mt = (nw >> 5) & 1; cblk = nw & 31;
        ne = counts[e]; base = offsets[e];
        if (mt * BM >= ne) return;
        W = Wall + (size_t)e * F_DIM * H_DIM;
    } else {
        cblk = blockIdx.x; mt = blockIdx.y;
        ne = T_TOK; base = 0;
        W = Wall;
    }
    const int c0 = cblk * 64;

    const int n4 = (tid & 15) * 4;
    const int kb = (tid >> 4) * 2;
    const int wcol = c0 + n4;
    int wr_off[4];
#pragma unroll
    for (int cc = 0; cc < 4; ++cc) {
        int n = n4 + cc;
        wr_off[cc] = n * 64 + BCHUNK(n, kb >> 3) * 8 + (kb & 7);
    }
    const int r0 = wn * 32 + lrow, r1 = wn * 32 + 16 + lrow;
    int rdB0[2], rdB1[2];
#pragma unroll
    for (int ks = 0; ks < 2; ++ks) {
        int kc = ks * 4 + lhi;
        rdB0[ks] = r0 * 64 + BCHUNK(r0, kc) * 8;
        rdB1[ks] = r1 * 64 + BCHUNK(r1, kc) * 8;
    }
    int rdA[4][2];
#pragma unroll
    for (int fm = 0; fm < 4; ++fm) {
        int arow = wm * 64 + fm * 16 + lrow;
#pragma unroll
        for (int ks = 0; ks < 2; ++ks) {
            int kc = ks * 4 + lhi;
            rdA[fm][ks] = arow * 64 + (((kc ^ ASWZ(arow)) & 7) << 3);
        }
    }
    const int m0_stride = ROUTED ? (2 * BM) : ((int)gridDim.y * BM);

    for (int m0 = mt * BM; m0 < ne; m0 += m0_stride) {
        __syncthreads();
        if (tid < BM) {
            int idx = m0 + tid;
            if (ROUTED) {
                toksS[tid] = (idx < ne) ? bucket_tok[base + idx] : 0;
            } else {
                sgS[tid] = sgate[(idx < ne) ? idx : (T_TOK - 1)];
            }
        }
        __syncthreads();

        int asrc[4];
#pragma unroll
        for (int i = 0; i < 4; ++i) {
            int row = wid * 32 + i * 8 + (lane >> 3);
            int grow = ROUTED ? min(base + m0 + row, NROWS - 1)
                              : min(m0 + row, T_TOK - 1);
            asrc[i] = grow * F_DIM + (((lane & 7) ^ ASWZ(row)) << 3);
        }

        f32x4 acc[4][2];
#pragma unroll
        for (int i = 0; i < 4; ++i) {
            acc[i][0] = (f32x4){0.f, 0.f, 0.f, 0.f};
            acc[i][1] = (f32x4){0.f, 0.f, 0.f, 0.f};
        }

        const int NT = F_DIM / 64;
        float4 b0 = *(const float4*)&W[(size_t)kb * H_DIM + wcol];
        float4 b1 = *(const float4*)&W[(size_t)(kb + 1) * H_DIM + wcol];

        for (int kt = 0; kt < NT; ++kt) {
            const int k0 = kt * 64;
            __syncthreads();
#pragma unroll
            for (int i = 0; i < 4; ++i)
                GLDS16(actb + asrc[i] + k0, &As[(wid * 32 + i * 8) * 64]);
#pragma unroll
            for (int cc = 0; cc < 4; ++cc)
                *(ushort2*)&Bs[wr_off[cc]] = make_ushort2(
                    f2bf(((const float*)&b0)[cc]), f2bf(((const float*)&b1)[cc]));
            {
                int knx = (kt + 1 < NT) ? (k0 + 64) : k0;
                b0 = *(const float4*)&W[(size_t)(knx + kb) * H_DIM + wcol];
                b1 = *(const float4*)&W[(size_t)(knx + kb + 1) * H_DIM + wcol];
            }
            __syncthreads();
#pragma unroll
            for (int ks = 0; ks < 2; ++ks) {
                short8v bf0 = *(const short8v*)&Bs[rdB0[ks]];
                short8v bf1 = *(const short8v*)&Bs[rdB1[ks]];
#pragma unroll
                for (int fm = 0; fm < 4; ++fm) {
                    short8v af = *(const short8v*)&As[rdA[fm][ks]];
                    acc[fm][0] = __builtin_amdgcn_mfma_f32_16x16x32_bf16(af, bf0, acc[fm][0], 0, 0, 0);
                    acc[fm][1] = __builtin_amdgcn_mfma_f32_16x16x32_bf16(af, bf1, acc[fm][1], 0, 0, 0);
                }
            }
        }

#pragma unroll
        for (int fm = 0; fm < 4; ++fm) {
#pragma unroll
            for (int fn = 0; fn < 2; ++fn) {
                int col = c0 + wn * 32 + fn * 16 + lrow;
#pragma unroll
                for (int i = 0; i < 4; ++i) {
                    int ml = wm * 64 + fm * 16 + lhi * 4 + i;
                    int idx = m0 + ml;
                    if (idx < ne) {
                        if (ROUTED) {
                            atomicAdd(&out[(size_t)toksS[ml] * H_DIM + col], acc[fm][fn][i]);
                        } else {
                            out[(size_t)idx * H_DIM + col] = sgS[ml] * acc[fm][fn][i];
                        }
                    }
                }
            }
        }
    }
}

// ---------------------------------------------------------------------------
extern "C" void kernel_launch(void* const* d_in, const int* in_sizes, int n_in,
                              void* d_out, int out_size, void* d_ws, size_t ws_size,
                              hipStream_t stream) {
    const float* x    = (const float*)d_in[0];
    const float* Wg   = (const float*)d_in[1];
    const float* Wgu  = (const float*)d_in[2];
    const float* Wd   = (const float*)d_in[3];
    const float* Wsgu = (const float*)d_in[4];
    const float* Wsd  = (const float*)d_in[5];
    float* out = (float*)d_out;

    char* p = (char*)d_ws;
    auto alloc = [&](size_t bytes) {
        char* r = p;
        p += (bytes + 255) & ~(size_t)255;
        return r;
    };
    int*   topk_idx   = (int*)  alloc((size_t)T_TOK * K_TOP * sizeof(int));
    float* topk_w     = (float*)alloc((size_t)T_TOK * K_TOP * sizeof(float));
    float* sgate      = (float*)alloc((size_t)T_TOK * sizeof(float));
    int*   counts     = (int*)  alloc((size_t)E_NUM * sizeof(int));
    int*   offsets    = (int*)  alloc((size_t)E_NUM * sizeof(int));
    int*   bucket_tok = (int*)  alloc((size_t)NROWS * sizeof(int));
    float* bucket_w   = (float*)alloc((size_t)NROWS * sizeof(float));
    unsigned short* xb    = (unsigned short*)alloc((size_t)T_TOK * H_DIM * sizeof(short));
    unsigned short* act_r = (unsigned short*)alloc((size_t)NROWS * F_DIM * sizeof(short));
    unsigned short* act_s = (unsigned short*)alloc((size_t)T_TOK * FS_DIM * sizeof(short));

    hipMemsetAsync(counts, 0, E_NUM * sizeof(int), stream);
    cvt_bf16_kernel<<<(T_TOK * H_DIM / 8 + 255) / 256, 256, 0, stream>>>(x, xb, T_TOK * H_DIM / 8);
    router_kernel<<<T_TOK, 64, 0, stream>>>(x, Wg, topk_idx, topk_w, sgate, counts);
    bucket_kernel<<<E_NUM, 256, 0, stream>>>(topk_idx, topk_w, counts, offsets, bucket_tok, bucket_w);

    // routed gate_up: 16 colblks x 64 experts x 2 m-tiles (overflow tile exits)
    gu_mfma_kernel<true><<<16 * E_NUM * 2, 512, 0, stream>>>(
        xb, Wgu, counts, offsets, bucket_tok, bucket_w, act_r);
    // shared gate_up: 16 colblks x 8 m-tiles
    gu_mfma_kernel<false><<<dim3(16, T_TOK / 256), 512, 0, stream>>>(
        xb, Wsgu, counts, offsets, bucket_tok, bucket_w, act_s);

    // shared down writes out first; routed down accumulates atomically on top
    down_mfma_kernel<false><<<dim3(32, T_TOK / 256), 512, 0, stream>>>(
        act_s, Wsd, counts, offsets, bucket_tok, sgate, out);
    down_mfma_kernel<true><<<32 * E_NUM * 2, 512, 0, stream>>>(
        act_r, Wd, counts, offsets, bucket_tok, sgate, out);
}

// Round 10
// 745.443 us; speedup vs baseline: 1.0996x; 1.0996x over previous
//
#include <hip/hip_runtime.h>
#include <hip/hip_bf16.h>
#include <math.h>

#define T_TOK 2048
#define H_DIM 2048
#define E_NUM 64
#define F_DIM 512
#define K_TOP 8
#define FS_DIM 512
#define NROWS (T_TOK * K_TOP)

typedef __attribute__((ext_vector_type(8))) short short8v;   // bf16x8 MFMA frag
typedef __attribute__((ext_vector_type(4))) float f32x4;     // MFMA accum

static __device__ __forceinline__ unsigned short f2bf(float f) {
    unsigned int u = __float_as_uint(f);
    u += 0x7fff + ((u >> 16) & 1);           // RNE to bf16
    return (unsigned short)(u >> 16);
}

// B tile [64n][64k]: 16B-chunk swizzle (row stride 128B, bank-neutral)
#define BCHUNK(row, k8) ((((k8) ^ ((row) + ((row) >> 3)))) & 7)
// A tile [256r][32k]: rows are 64B (4 chunks); swizzle chunk ^= (r>>1)&3
#define ASW32(r) (((r) >> 1) & 3)

typedef const unsigned int __attribute__((address_space(1))) gu32;
typedef unsigned int __attribute__((address_space(3))) lu32;
// async global->LDS, 16B per lane; dest = wave-uniform base + lane*16
#define GLDS16(gsrc, ldst) \
    __builtin_amdgcn_global_load_lds((gu32*)(gsrc), (lu32*)(ldst), 16, 0, 0)

// ---------------------------------------------------------------------------
// x (fp32) -> bf16 copy, vectorized 8/thread
// ---------------------------------------------------------------------------
__global__ __launch_bounds__(256) void cvt_bf16_kernel(
    const float* __restrict__ in, unsigned short* __restrict__ out, int n8)
{
    int i = blockIdx.x * 256 + threadIdx.x;
    if (i < n8) {
        const float4* p = (const float4*)(in + (size_t)i * 8);
        float4 v0 = p[0], v1 = p[1];
        ushort4 a = make_ushort4(f2bf(v0.x), f2bf(v0.y), f2bf(v0.z), f2bf(v0.w));
        ushort4 b = make_ushort4(f2bf(v1.x), f2bf(v1.y), f2bf(v1.z), f2bf(v1.w));
        ushort4* q = (ushort4*)(out + (size_t)i * 8);
        q[0] = a; q[1] = b;
    }
}

// ---------------------------------------------------------------------------
// Router: one wave per token (fp32 math, exact top-k vs reference).
// ---------------------------------------------------------------------------
__global__ __launch_bounds__(64) void router_kernel(
    const float* __restrict__ x, const float* __restrict__ Wg,
    int* __restrict__ topk_idx, float* __restrict__ topk_w,
    float* __restrict__ sgate, int* __restrict__ counts)
{
    const int t = blockIdx.x;
    const int lane = threadIdx.x;
    const float* xr = x + (size_t)t * H_DIM;

    float a0 = 0.f, a1 = 0.f, a2 = 0.f, a3 = 0.f;
    for (int h = 0; h < H_DIM; h += 4) {
        float4 xv = *(const float4*)&xr[h];
        a0 += xv.x * Wg[(h + 0) * 65 + lane];
        a1 += xv.y * Wg[(h + 1) * 65 + lane];
        a2 += xv.z * Wg[(h + 2) * 65 + lane];
        a3 += xv.w * Wg[(h + 3) * 65 + lane];
    }
    float logit = (a0 + a1) + (a2 + a3);

    float a64 = 0.f;
    for (int h = lane; h < H_DIM; h += 64) a64 += xr[h] * Wg[h * 65 + 64];
#pragma unroll
    for (int off = 32; off >= 1; off >>= 1) a64 += __shfl_xor(a64, off);

    float v = logit;
    float selv[K_TOP]; int seli[K_TOP];
#pragma unroll
    for (int k = 0; k < K_TOP; ++k) {
        float mv = v; int mi = lane;
#pragma unroll
        for (int off = 32; off >= 1; off >>= 1) {
            float ov = __shfl_xor(mv, off);
            int   oi = __shfl_xor(mi, off);
            if (ov > mv || (ov == mv && oi < mi)) { mv = ov; mi = oi; }
        }
        selv[k] = mv; seli[k] = mi;
        if (lane == mi) v = -INFINITY;
    }

    if (lane == 0) {
        float m = selv[0];
        float w[K_TOP]; float s = 0.f;
#pragma unroll
        for (int k = 0; k < K_TOP; ++k) { w[k] = __expf(selv[k] - m); s += w[k]; }
        float inv = 1.f / s;
#pragma unroll
        for (int k = 0; k < K_TOP; ++k) {
            topk_idx[t * K_TOP + k] = seli[k];
            topk_w[t * K_TOP + k] = w[k] * inv;
            atomicAdd(&counts[seli[k]], 1);
        }
        sgate[t] = 1.f / (1.f + __expf(-a64));
    }
}

// ---------------------------------------------------------------------------
// Deterministic per-expert compaction.
// ---------------------------------------------------------------------------
__global__ __launch_bounds__(256) void bucket_kernel(
    const int* __restrict__ topk_idx, const float* __restrict__ topk_w,
    const int* __restrict__ counts, int* __restrict__ offsets,
    int* __restrict__ bucket_tok, float* __restrict__ bucket_w)
{
    const int e = blockIdx.x, thr = threadIdx.x;
    __shared__ int cnt[256];
    __shared__ int base_s;
    const int q0 = thr * 64;
    int c = 0;
    for (int q = 0; q < 64; ++q) c += (topk_idx[q0 + q] == e) ? 1 : 0;
    cnt[thr] = c;
    __syncthreads();
    if (thr == 0) {
        int off = 0;
        for (int i = 0; i < e; ++i) off += counts[i];
        offsets[e] = off;
        base_s = off;
        int run = 0;
        for (int i = 0; i < 256; ++i) { int tval = cnt[i]; cnt[i] = run; run += tval; }
    }
    __syncthreads();
    int pos = base_s + cnt[thr];
    for (int q = 0; q < 64; ++q) {
        int pp = q0 + q;
        if (topk_idx[pp] == e) {
            bucket_tok[pos] = pp >> 3;
            bucket_w[pos] = topk_w[pp];
            ++pos;
        }
    }
}

// ---------------------------------------------------------------------------
// gate_up + SiLU*u*topw — stage-ahead double-buffered pipeline, one
// __syncthreads per K32 half-step (full drain => memory-safe):
//   half-step s:  GLDS A(s+1)->A[(s+1)&1];
//                 if s odd: ds_write B(kt+1)->B[(kt+1)&1]; issue W(kt+2);
//                 compute(s) from A[s&1], B[kt&1];  __syncthreads();
// GLDS/W latency overlaps the compute phase instead of draining immediately.
// LDS 50KB -> 3 blocks/CU. Block 512 thr = 8 waves (4 wm x 2 wn).
// ---------------------------------------------------------------------------
template<bool ROUTED>
__global__ __launch_bounds__(512, 6) void gu_mfma_kernel(
    const unsigned short* __restrict__ xb,
    const float* __restrict__ Wall,
    const int* __restrict__ counts, const int* __restrict__ offsets,
    const int* __restrict__ bucket_tok, const float* __restrict__ bucket_w,
    unsigned short* __restrict__ actout)
{
    constexpr int BM = 256;
    __shared__ __align__(16) unsigned short As[2][BM * 32];  // 2 x 16 KB
    __shared__ __align__(16) unsigned short Bs[2][64 * 64];  // 2 x 8 KB
    __shared__ int   toksS[BM];
    __shared__ float twsS[BM];

    const int tid  = threadIdx.x;
    const int lane = tid & 63;
    const int wid  = tid >> 6;
    const int wm = wid >> 1, wn = wid & 1;
    const int lrow = lane & 15, lhi = lane >> 4;

    int cblk, mt, ne, base;
    const float* W;
    if (ROUTED) {
        int nw = (blockIdx.x & 7) * ((int)gridDim.x >> 3) + (blockIdx.x >> 3);
        int e = nw >> 5; mt = (nw >> 4) & 1; cblk = nw & 15;
        ne = counts[e]; base = offsets[e];
        if (mt * BM >= ne) return;                 // overflow tile unused
        W = Wall + (size_t)e * H_DIM * (2 * F_DIM);
    } else {
        cblk = blockIdx.x; mt = blockIdx.y;
        ne = T_TOK; base = 0;
        W = Wall;
    }
    const int c0 = cblk * 32;               // act-col base

    // W staging geometry (per K64 tile): thread covers 4 n-cols x 2 k-rows
    const int n4 = (tid & 15) * 4;
    const int kb = (tid >> 4) * 2;
    const int n5 = n4 & 31;
    const int wcol = ((n5 < 16) ? 0 : (F_DIM - 16)) + c0 + (n4 >> 5) * 16 + n5;
    int wr_off[4];
#pragma unroll
    for (int cc = 0; cc < 4; ++cc) {
        int n = n4 + cc;
        wr_off[cc] = n * 64 + BCHUNK(n, kb >> 3) * 8 + (kb & 7);
    }
    // B read offsets per ks in {0,1}
    const int rg = wn * 32 + lrow, ru = wn * 32 + 16 + lrow;
    int rdBg[2], rdBu[2];
#pragma unroll
    for (int ks = 0; ks < 2; ++ks) {
        int kc = ks * 4 + lhi;
        rdBg[ks] = rg * 64 + BCHUNK(rg, kc) * 8;
        rdBu[ks] = ru * 64 + BCHUNK(ru, kc) * 8;
    }
    // A read offsets (per fm), within a [256][32] half-tile
    int rdA[4];
#pragma unroll
    for (int fm = 0; fm < 4; ++fm) {
        int arow = wm * 64 + fm * 16 + lrow;
        rdA[fm] = arow * 32 + ((lhi ^ ASW32(arow)) << 3);
    }
    // A staging rows for this lane (2 GLDS issues per wave per half-step)
    const int ar0 = wid * 32 + (lane >> 2);
    const int ar1 = ar0 + 16;
    const int NT   = H_DIM / 64;   // K64 tiles
    const int SMAX = H_DIM / 32;   // half-steps
    const int m0_stride = ROUTED ? (2 * BM) : ((int)gridDim.y * BM);

    for (int m0 = mt * BM; m0 < ne; m0 += m0_stride) {
        __syncthreads();
        if (tid < BM) {
            int idx = m0 + tid; bool v = idx < ne;
            if (ROUTED) {
                toksS[tid] = v ? bucket_tok[base + idx] : bucket_tok[base];
                twsS[tid]  = v ? bucket_w[base + idx] : 0.f;
            } else {
                toksS[tid] = v ? idx : (T_TOK - 1);
                twsS[tid]  = 1.f;
            }
        }
        __syncthreads();

        // per-lane GLDS source base offsets (pre-swizzled, half-invariant)
        const int src0 = toksS[ar0] * H_DIM + (((lane & 3) ^ ASW32(ar0)) << 3);
        const int src1 = toksS[ar1] * H_DIM + (((lane & 3) ^ ASW32(ar1)) << 3);

        f32x4 acc[4][2];
#pragma unroll
        for (int i = 0; i < 4; ++i) {
            acc[i][0] = (f32x4){0.f, 0.f, 0.f, 0.f};
            acc[i][1] = (f32x4){0.f, 0.f, 0.f, 0.f};
        }

        // prologue: A(0) -> A[0]; B(0) -> B[0]; issue W(1)
        float4 b0 = *(const float4*)&W[(size_t)kb * (2 * F_DIM) + wcol];
        float4 b1 = *(const float4*)&W[(size_t)(kb + 1) * (2 * F_DIM) + wcol];
        GLDS16(xb + src0, &As[0][(wid * 32) * 32]);
        GLDS16(xb + src1, &As[0][(wid * 32 + 16) * 32]);
#pragma unroll
        for (int cc = 0; cc < 4; ++cc)
            *(ushort2*)&Bs[0][wr_off[cc]] = make_ushort2(
                f2bf(((const float*)&b0)[cc]), f2bf(((const float*)&b1)[cc]));
        b0 = *(const float4*)&W[(size_t)(64 + kb) * (2 * F_DIM) + wcol];
        b1 = *(const float4*)&W[(size_t)(64 + kb + 1) * (2 * F_DIM) + wcol];
        __syncthreads();

        for (int s = 0; s < SMAX; ++s) {
            const int kt = s >> 1;
            // stage A(s+1) into the other half-buffer (overlaps compute below)
            if (s + 1 < SMAX) {
                const int kof = (s + 1) * 32;
                GLDS16(xb + src0 + kof, &As[(s + 1) & 1][(wid * 32) * 32]);
                GLDS16(xb + src1 + kof, &As[(s + 1) & 1][(wid * 32 + 16) * 32]);
            }
            // stage B(kt+1) at odd halves; issue W(kt+2)
            if ((s & 1) && (kt + 1 < NT)) {
#pragma unroll
                for (int cc = 0; cc < 4; ++cc)
                    *(ushort2*)&Bs[(kt + 1) & 1][wr_off[cc]] = make_ushort2(
                        f2bf(((const float*)&b0)[cc]), f2bf(((const float*)&b1)[cc]));
                int knx = (kt + 2 < NT) ? (kt + 2) * 64 : (NT - 1) * 64;
                b0 = *(const float4*)&W[(size_t)(knx + kb) * (2 * F_DIM) + wcol];
                b1 = *(const float4*)&W[(size_t)(knx + kb + 1) * (2 * F_DIM) + wcol];
            }
            __builtin_amdgcn_sched_barrier(0);   // pin staging issue before compute
            // compute(s)
            const unsigned short* A_ = As[s & 1];
            const unsigned short* B_ = Bs[kt & 1];
            const int ks = s & 1;
            short8v bg = *(const short8v*)&B_[rdBg[ks]];
            short8v bu = *(const short8v*)&B_[rdBu[ks]];
#pragma unroll
            for (int fm = 0; fm < 4; ++fm) {
                short8v af = *(const short8v*)&A_[rdA[fm]];
                acc[fm][0] = __builtin_amdgcn_mfma_f32_16x16x32_bf16(af, bg, acc[fm][0], 0, 0, 0);
                acc[fm][1] = __builtin_amdgcn_mfma_f32_16x16x32_bf16(af, bu, acc[fm][1], 0, 0, 0);
            }
            __syncthreads();                     // drains GLDS(s+1) + B writes
        }

        // epilogue: silu(g)*u*topw -> bf16 act
        const int acol = c0 + wn * 16 + lrow;
#pragma unroll
        for (int fm = 0; fm < 4; ++fm) {
#pragma unroll
            for (int i = 0; i < 4; ++i) {
                int ml = wm * 64 + fm * 16 + lhi * 4 + i;
                int idx = m0 + ml;
                if (idx < ne) {
                    float gv = acc[fm][0][i], uv = acc[fm][1][i];
                    float s = gv / (1.f + __expf(-gv));
                    float val = s * uv * twsS[ml];
                    size_t orow = ROUTED ? (size_t)(base + idx) : (size_t)idx;
                    actout[orow * F_DIM + acol] = f2bf(val);
                }
            }
        }
    }
}

// ---------------------------------------------------------------------------
// down-proj, same pipelined structure (K=512 -> 16 half-steps).
// ROUTED: atomicAdd scatter to out; shared: plain store * sigmoid.
// ---------------------------------------------------------------------------
template<bool ROUTED>
__global__ __launch_bounds__(512, 6) void down_mfma_kernel(
    const unsigned short* __restrict__ actb,
    const float* __restrict__ Wall,
    const int* __restrict__ counts, const int* __restrict__ offsets,
    const int* __restrict__ bucket_tok, const float* __restrict__ sgate,
    float* __restrict__ out)
{
    constexpr int BM = 256;
    __shared__ __align__(16) unsigned short As[2][BM * 32];
    __shared__ __align__(16) unsigned short Bs[2][64 * 64];
    __shared__ int   toksS[BM];
    __shared__ float sgS[BM];

    const int tid  = threadIdx.x;
    const int lane = tid & 63;
    const int wid  = tid >> 6;
    const int wm = wid >> 1, wn = wid & 1;
    const int lrow = lane & 15, lhi = lane >> 4;

    int cblk, mt, ne, base;
    const float* W;
    if (ROUTED) {
        int nw = (blockIdx.x & 7) * ((int)gridDim.x >> 3) + (blockIdx.x >> 3);
        int e = nw >> 6; mt = (nw >> 5) & 1; cblk = nw & 31;
        ne = counts[e]; base = offsets[e];
        if (mt * BM >= ne) return;
        W = Wall + (size_t)e * F_DIM * H_DIM;
    } else {
        cblk = blockIdx.x; mt = blockIdx.y;
        ne = T_TOK; base = 0;
        W = Wall;
    }
    const int c0 = cblk * 64;

    const int n4 = (tid & 15) * 4;
    const int kb = (tid >> 4) * 2;
    const int wcol = c0 + n4;
    int wr_off[4];
#pragma unroll
    for (int cc = 0; cc < 4; ++cc) {
        int n = n4 + cc;
        wr_off[cc] = n * 64 + BCHUNK(n, kb >> 3) * 8 + (kb & 7);
    }
    const int r0 = wn * 32 + lrow, r1 = wn * 32 + 16 + lrow;
    int rdB0[2], rdB1[2];
#pragma unroll
    for (int ks = 0; ks < 2; ++ks) {
        int kc = ks * 4 + lhi;
        rdB0[ks] = r0 * 64 + BCHUNK(r0, kc) * 8;
        rdB1[ks] = r1 * 64 + BCHUNK(r1, kc) * 8;
    }
    int rdA[4];
#pragma unroll
    for (int fm = 0; fm < 4; ++fm) {
        int arow = wm * 64 + fm * 16 + lrow;
        rdA[fm] = arow * 32 + ((lhi ^ ASW32(arow)) << 3);
    }
    const int ar0 = wid * 32 + (lane >> 2);
    const int ar1 = ar0 + 16;
    const int NT   = F_DIM / 64;
    const int SMAX = F_DIM / 32;
    const int m0_stride = ROUTED ? (2 * BM) : ((int)gridDim.y * BM);

    for (int m0 = mt * BM; m0 < ne; m0 += m0_stride) {
        __syncthreads();
        if (tid < BM) {
            int idx = m0 + tid;
            if (ROUTED) {
                toksS[tid] = (idx < ne) ? bucket_tok[base + idx] : 0;
            } else {
                sgS[tid] = sgate[(idx < ne) ? idx : (T_TOK - 1)];
            }
        }
        __syncthreads();

        int g0 = ROUTED ? min(base + m0 + ar0, NROWS - 1) : min(m0 + ar0, T_TOK - 1);
        int g1 = ROUTED ? min(base + m0 + ar1, NROWS - 1) : min(m0 + ar1, T_TOK - 1);
        const int src0 = g0 * F_DIM + (((lane & 3) ^ ASW32(ar0)) << 3);
        const int src1 = g1 * F_DIM + (((lane & 3) ^ ASW32(ar1)) << 3);

        f32x4 acc[4][2];
#pragma unroll
        for (int i = 0; i < 4; ++i) {
            acc[i][0] = (f32x4){0.f, 0.f, 0.f, 0.f};
            acc[i][1] = (f32x4){0.f, 0.f, 0.f, 0.f};
        }

        float4 b0 = *(const float4*)&W[(size_t)kb * H_DIM + wcol];
        float4 b1 = *(const float4*)&W[(size_t)(kb + 1) * H_DIM + wcol];
        GLDS16(actb + src0, &As[0][(wid * 32) * 32]);
        GLDS16(actb + src1, &As[0][(wid * 32 + 16) * 32]);
#pragma unroll
        for (int cc = 0; cc < 4; ++cc)
            *(ushort2*)&Bs[0][wr_off[cc]] = make_ushort2(
                f2bf(((const float*)&b0)[cc]), f2bf(((const float*)&b1)[cc]));
        b0 = *(const float4*)&W[(size_t)(64 + kb) * H_DIM + wcol];
        b1 = *(const float4*)&W[(size_t)(64 + kb + 1) * H_DIM + wcol];
        __syncthreads();

        for (int s = 0; s < SMAX; ++s) {
            const int kt = s >> 1;
            if (s + 1 < SMAX) {
                const int kof = (s + 1) * 32;
                GLDS16(actb + src0 + kof, &As[(s + 1) & 1][(wid * 32) * 32]);
                GLDS16(actb + src1 + kof, &As[(s + 1) & 1][(wid * 32 + 16) * 32]);
            }
            if ((s & 1) && (kt + 1 < NT)) {
#pragma unroll
                for (int cc = 0; cc < 4; ++cc)
                    *(ushort2*)&Bs[(kt + 1) & 1][wr_off[cc]] = make_ushort2(
                        f2bf(((const float*)&b0)[cc]), f2bf(((const float*)&b1)[cc]));
                int knx = (kt + 2 < NT) ? (kt + 2) * 64 : (NT - 1) * 64;
                b0 = *(const float4*)&W[(size_t)(knx + kb) * H_DIM + wcol];
                b1 = *(const float4*)&W[(size_t)(knx + kb + 1) * H_DIM + wcol];
            }
            __builtin_amdgcn_sched_barrier(0);
            const unsigned short* A_ = As[s & 1];
            const unsigned short* B_ = Bs[kt & 1];
            const int ks = s & 1;
            short8v bf0 = *(const short8v*)&B_[rdB0[ks]];
            short8v bf1 = *(const short8v*)&B_[rdB1[ks]];
#pragma unroll
            for (int fm = 0; fm < 4; ++fm) {
                short8v af = *(const short8v*)&A_[rdA[fm]];
                acc[fm][0] = __builtin_amdgcn_mfma_f32_16x16x32_bf16(af, bf0, acc[fm][0], 0, 0, 0);
                acc[fm][1] = __builtin_amdgcn_mfma_f32_16x16x32_bf16(af, bf1, acc[fm][1], 0, 0, 0);
            }
            __syncthreads();
        }

#pragma unroll
        for (int fm = 0; fm < 4; ++fm) {
#pragma unroll
            for (int fn = 0; fn < 2; ++fn) {
                int col = c0 + wn * 32 + fn * 16 + lrow;
#pragma unroll
                for (int i = 0; i < 4; ++i) {
                    int ml = wm * 64 + fm * 16 + lhi * 4 + i;
                    int idx = m0 + ml;
                    if (idx < ne) {
                        if (ROUTED) {
                            atomicAdd(&out[(size_t)toksS[ml] * H_DIM + col], acc[fm][fn][i]);
                        } else {
                            out[(size_t)idx * H_DIM + col] = sgS[ml] * acc[fm][fn][i];
                        }
                    }
                }
            }
        }
    }
}

// ---------------------------------------------------------------------------
extern "C" void kernel_launch(void* const* d_in, const int* in_sizes, int n_in,
                              void* d_out, int out_size, void* d_ws, size_t ws_size,
                              hipStream_t stream) {
    const float* x    = (const float*)d_in[0];
    const float* Wg   = (const float*)d_in[1];
    const float* Wgu  = (const float*)d_in[2];
    const float* Wd   = (const float*)d_in[3];
    const float* Wsgu = (const float*)d_in[4];
    const float* Wsd  = (const float*)d_in[5];
    float* out = (float*)d_out;

    char* p = (char*)d_ws;
    auto alloc = [&](size_t bytes) {
        char* r = p;
        p += (bytes + 255) & ~(size_t)255;
        return r;
    };
    int*   topk_idx   = (int*)  alloc((size_t)T_TOK * K_TOP * sizeof(int));
    float* topk_w     = (float*)alloc((size_t)T_TOK * K_TOP * sizeof(float));
    float* sgate      = (float*)alloc((size_t)T_TOK * sizeof(float));
    int*   counts     = (int*)  alloc((size_t)E_NUM * sizeof(int));
    int*   offsets    = (int*)  alloc((size_t)E_NUM * sizeof(int));
    int*   bucket_tok = (int*)  alloc((size_t)NROWS * sizeof(int));
    float* bucket_w   = (float*)alloc((size_t)NROWS * sizeof(float));
    unsigned short* xb    = (unsigned short*)alloc((size_t)T_TOK * H_DIM * sizeof(short));
    unsigned short* act_r = (unsigned short*)alloc((size_t)NROWS * F_DIM * sizeof(short));
    unsigned short* act_s = (unsigned short*)alloc((size_t)T_TOK * FS_DIM * sizeof(short));

    hipMemsetAsync(counts, 0, E_NUM * sizeof(int), stream);
    cvt_bf16_kernel<<<(T_TOK * H_DIM / 8 + 255) / 256, 256, 0, stream>>>(x, xb, T_TOK * H_DIM / 8);
    router_kernel<<<T_TOK, 64, 0, stream>>>(x, Wg, topk_idx, topk_w, sgate, counts);
    bucket_kernel<<<E_NUM, 256, 0, stream>>>(topk_idx, topk_w, counts, offsets, bucket_tok, bucket_w);

    // routed gate_up: 16 colblks x 64 experts x 2 m-tiles (overflow tile exits)
    gu_mfma_kernel<true><<<16 * E_NUM * 2, 512, 0, stream>>>(
        xb, Wgu, counts, offsets, bucket_tok, bucket_w, act_r);
    // shared gate_up: 16 colblks x 8 m-tiles
    gu_mfma_kernel<false><<<dim3(16, T_TOK / 256), 512, 0, stream>>>(
        xb, Wsgu, counts, offsets, bucket_tok, bucket_w, act_s);

    // shared down writes out first; routed down accumulates atomically on top
    down_mfma_kernel<false><<<dim3(32, T_TOK / 256), 512, 0, stream>>>(
        act_s, Wsd, counts, offsets, bucket_tok, sgate, out);
    down_mfma_kernel<true><<<32 * E_NUM * 2, 512, 0, stream>>>(
        act_r, Wd, counts, offsets, bucket_tok, sgate, out);
}

// Round 11
// 741.395 us; speedup vs baseline: 1.1056x; 1.0055x over previous
//
#include <hip/hip_runtime.h>
#include <hip/hip_bf16.h>
#include <math.h>

#define T_TOK 2048
#define H_DIM 2048
#define E_NUM 64
#define F_DIM 512
#define K_TOP 8
#define FS_DIM 512
#define NROWS (T_TOK * K_TOP)

typedef __attribute__((ext_vector_type(8))) short short8v;   // bf16x8 MFMA frag
typedef __attribute__((ext_vector_type(4))) float f32x4;     // MFMA accum

static __device__ __forceinline__ unsigned short f2bf(float f) {
    unsigned int u = __float_as_uint(f);
    u += 0x7fff + ((u >> 16) & 1);           // RNE to bf16
    return (unsigned short)(u >> 16);
}

// B tile [N][64k]: 16B-chunk swizzle (row stride 128B, bank-neutral)
#define BCHUNK(row, k8) ((((k8) ^ ((row) + ((row) >> 3)))) & 7)
// A tile [256r][32k]: rows are 64B (4 chunks); swizzle chunk ^= (r>>1)&3
#define ASW32(r) (((r) >> 1) & 3)

typedef const unsigned int __attribute__((address_space(1))) gu32;
typedef unsigned int __attribute__((address_space(3))) lu32;
// async global->LDS, 16B per lane; dest = wave-uniform base + lane*16
#define GLDS16(gsrc, ldst) \
    __builtin_amdgcn_global_load_lds((gu32*)(gsrc), (lu32*)(ldst), 16, 0, 0)

// ---------------------------------------------------------------------------
// x (fp32) -> bf16 copy, vectorized 8/thread
// ---------------------------------------------------------------------------
__global__ __launch_bounds__(256) void cvt_bf16_kernel(
    const float* __restrict__ in, unsigned short* __restrict__ out, int n8)
{
    int i = blockIdx.x * 256 + threadIdx.x;
    if (i < n8) {
        const float4* p = (const float4*)(in + (size_t)i * 8);
        float4 v0 = p[0], v1 = p[1];
        ushort4 a = make_ushort4(f2bf(v0.x), f2bf(v0.y), f2bf(v0.z), f2bf(v0.w));
        ushort4 b = make_ushort4(f2bf(v1.x), f2bf(v1.y), f2bf(v1.z), f2bf(v1.w));
        ushort4* q = (ushort4*)(out + (size_t)i * 8);
        q[0] = a; q[1] = b;
    }
}

// ---------------------------------------------------------------------------
// Router: one wave per token (fp32 math, exact top-k vs reference).
// ---------------------------------------------------------------------------
__global__ __launch_bounds__(64) void router_kernel(
    const float* __restrict__ x, const float* __restrict__ Wg,
    int* __restrict__ topk_idx, float* __restrict__ topk_w,
    float* __restrict__ sgate, int* __restrict__ counts)
{
    const int t = blockIdx.x;
    const int lane = threadIdx.x;
    const float* xr = x + (size_t)t * H_DIM;

    float a0 = 0.f, a1 = 0.f, a2 = 0.f, a3 = 0.f;
    for (int h = 0; h < H_DIM; h += 4) {
        float4 xv = *(const float4*)&xr[h];
        a0 += xv.x * Wg[(h + 0) * 65 + lane];
        a1 += xv.y * Wg[(h + 1) * 65 + lane];
        a2 += xv.z * Wg[(h + 2) * 65 + lane];
        a3 += xv.w * Wg[(h + 3) * 65 + lane];
    }
    float logit = (a0 + a1) + (a2 + a3);

    float a64 = 0.f;
    for (int h = lane; h < H_DIM; h += 64) a64 += xr[h] * Wg[h * 65 + 64];
#pragma unroll
    for (int off = 32; off >= 1; off >>= 1) a64 += __shfl_xor(a64, off);

    float v = logit;
    float selv[K_TOP]; int seli[K_TOP];
#pragma unroll
    for (int k = 0; k < K_TOP; ++k) {
        float mv = v; int mi = lane;
#pragma unroll
        for (int off = 32; off >= 1; off >>= 1) {
            float ov = __shfl_xor(mv, off);
            int   oi = __shfl_xor(mi, off);
            if (ov > mv || (ov == mv && oi < mi)) { mv = ov; mi = oi; }
        }
        selv[k] = mv; seli[k] = mi;
        if (lane == mi) v = -INFINITY;
    }

    if (lane == 0) {
        float m = selv[0];
        float w[K_TOP]; float s = 0.f;
#pragma unroll
        for (int k = 0; k < K_TOP; ++k) { w[k] = __expf(selv[k] - m); s += w[k]; }
        float inv = 1.f / s;
#pragma unroll
        for (int k = 0; k < K_TOP; ++k) {
            topk_idx[t * K_TOP + k] = seli[k];
            topk_w[t * K_TOP + k] = w[k] * inv;
            atomicAdd(&counts[seli[k]], 1);
        }
        sgate[t] = 1.f / (1.f + __expf(-a64));
    }
}

// ---------------------------------------------------------------------------
// Deterministic per-expert compaction.
// ---------------------------------------------------------------------------
__global__ __launch_bounds__(256) void bucket_kernel(
    const int* __restrict__ topk_idx, const float* __restrict__ topk_w,
    const int* __restrict__ counts, int* __restrict__ offsets,
    int* __restrict__ bucket_tok, float* __restrict__ bucket_w)
{
    const int e = blockIdx.x, thr = threadIdx.x;
    __shared__ int cnt[256];
    __shared__ int base_s;
    const int q0 = thr * 64;
    int c = 0;
    for (int q = 0; q < 64; ++q) c += (topk_idx[q0 + q] == e) ? 1 : 0;
    cnt[thr] = c;
    __syncthreads();
    if (thr == 0) {
        int off = 0;
        for (int i = 0; i < e; ++i) off += counts[i];
        offsets[e] = off;
        base_s = off;
        int run = 0;
        for (int i = 0; i < 256; ++i) { int tval = cnt[i]; cnt[i] = run; run += tval; }
    }
    __syncthreads();
    int pos = base_s + cnt[thr];
    for (int q = 0; q < 64; ++q) {
        int pp = q0 + q;
        if (topk_idx[pp] == e) {
            bucket_tok[pos] = pp >> 3;
            bucket_w[pos] = topk_w[pp];
            ++pos;
        }
    }
}

// ---------------------------------------------------------------------------
// gate_up + SiLU*u*topw — round-10 stage-ahead structure, BN=64 act cols
// (128 W cols). B tile [128 n][64 k] rows = [g lo | u lo | g hi | u hi] in
// 32-row groups. 8 waves (4 wm x 2 wn); wave = 64 rows x 32 act cols,
// acc[4][4]; 16 MFMA per K32 half-step. One __syncthreads per half-step.
// ---------------------------------------------------------------------------
template<bool ROUTED>
__global__ __launch_bounds__(512, 4) void gu_mfma_kernel(
    const unsigned short* __restrict__ xb,
    const float* __restrict__ Wall,
    const int* __restrict__ counts, const int* __restrict__ offsets,
    const int* __restrict__ bucket_tok, const float* __restrict__ bucket_w,
    unsigned short* __restrict__ actout)
{
    constexpr int BM = 256;
    __shared__ __align__(16) unsigned short As[2][BM * 32];   // 2 x 16 KB
    __shared__ __align__(16) unsigned short Bs[2][128 * 64];  // 2 x 16 KB
    __shared__ int   toksS[BM];
    __shared__ float twsS[BM];

    const int tid  = threadIdx.x;
    const int lane = tid & 63;
    const int wid  = tid >> 6;
    const int wm = wid >> 1, wn = wid & 1;
    const int lrow = lane & 15, lhi = lane >> 4;

    int cblk, mt, ne, base;
    const float* W;
    if (ROUTED) {
        int nw = (blockIdx.x & 7) * ((int)gridDim.x >> 3) + (blockIdx.x >> 3);
        int e = nw >> 4; mt = (nw >> 3) & 1; cblk = nw & 7;
        ne = counts[e]; base = offsets[e];
        if (mt * BM >= ne) return;
        W = Wall + (size_t)e * H_DIM * (2 * F_DIM);
    } else {
        cblk = blockIdx.x; mt = blockIdx.y;
        ne = T_TOK; base = 0;
        W = Wall;
    }
    const int c0 = cblk * 64;               // act-col base (BN=64)

    // B staging: thread covers 4 n-rows x 4 k (one float4 per k-row)
    const int n4 = (tid & 31) * 4;          // 0..124
    const int kq = (tid >> 5) * 4;          // 0..60
    const int grp = n4 >> 5;                // 0..3 -> {g lo, u lo, g hi, u hi}
    const int srccol = c0 + (grp >> 1) * 32 + (n4 & 31) + ((grp & 1) ? F_DIM : 0);
    int wrB[4];
#pragma unroll
    for (int cc = 0; cc < 4; ++cc) {
        int n = n4 + cc;
        wrB[cc] = n * 64 + BCHUNK(n, kq >> 3) * 8 + (kq & 7);
    }
    // B read offsets: rows r = wn*64 + fn*16 + lrow, per ks
    int rdB[4][2];
#pragma unroll
    for (int fn = 0; fn < 4; ++fn) {
        int r = wn * 64 + fn * 16 + lrow;
#pragma unroll
        for (int ks = 0; ks < 2; ++ks) {
            int kc = ks * 4 + lhi;
            rdB[fn][ks] = r * 64 + BCHUNK(r, kc) * 8;
        }
    }
    // A read offsets within [256][32] half-tile
    int rdA[4];
#pragma unroll
    for (int fm = 0; fm < 4; ++fm) {
        int arow = wm * 64 + fm * 16 + lrow;
        rdA[fm] = arow * 32 + ((lhi ^ ASW32(arow)) << 3);
    }
    const int ar0 = wid * 32 + (lane >> 2);
    const int ar1 = ar0 + 16;
    const int NT   = H_DIM / 64;
    const int SMAX = H_DIM / 32;
    const int m0_stride = ROUTED ? (2 * BM) : ((int)gridDim.y * BM);

    for (int m0 = mt * BM; m0 < ne; m0 += m0_stride) {
        __syncthreads();
        if (tid < BM) {
            int idx = m0 + tid; bool v = idx < ne;
            if (ROUTED) {
                toksS[tid] = v ? bucket_tok[base + idx] : bucket_tok[base];
                twsS[tid]  = v ? bucket_w[base + idx] : 0.f;
            } else {
                toksS[tid] = v ? idx : (T_TOK - 1);
                twsS[tid]  = 1.f;
            }
        }
        __syncthreads();

        const int src0 = toksS[ar0] * H_DIM + (((lane & 3) ^ ASW32(ar0)) << 3);
        const int src1 = toksS[ar1] * H_DIM + (((lane & 3) ^ ASW32(ar1)) << 3);

        f32x4 acc[4][4];
#pragma unroll
        for (int i = 0; i < 4; ++i)
#pragma unroll
            for (int j = 0; j < 4; ++j) acc[i][j] = (f32x4){0.f, 0.f, 0.f, 0.f};

        // prologue: W(0)->Bs[0]; A(0)->As[0]; issue W(1)
        float4 bq[4];
#pragma unroll
        for (int i = 0; i < 4; ++i)
            bq[i] = *(const float4*)&W[(size_t)(kq + i) * (2 * F_DIM) + srccol];
        GLDS16(xb + src0, &As[0][(wid * 32) * 32]);
        GLDS16(xb + src1, &As[0][(wid * 32 + 16) * 32]);
#pragma unroll
        for (int cc = 0; cc < 4; ++cc)
            *(ushort4*)&Bs[0][wrB[cc]] = make_ushort4(
                f2bf(((const float*)&bq[0])[cc]), f2bf(((const float*)&bq[1])[cc]),
                f2bf(((const float*)&bq[2])[cc]), f2bf(((const float*)&bq[3])[cc]));
#pragma unroll
        for (int i = 0; i < 4; ++i)
            bq[i] = *(const float4*)&W[(size_t)(64 + kq + i) * (2 * F_DIM) + srccol];
        __syncthreads();

        for (int s = 0; s < SMAX; ++s) {
            const int kt = s >> 1;
            if (s + 1 < SMAX) {
                const int kof = (s + 1) * 32;
                GLDS16(xb + src0 + kof, &As[(s + 1) & 1][(wid * 32) * 32]);
                GLDS16(xb + src1 + kof, &As[(s + 1) & 1][(wid * 32 + 16) * 32]);
            }
            if ((s & 1) && (kt + 1 < NT)) {
#pragma unroll
                for (int cc = 0; cc < 4; ++cc)
                    *(ushort4*)&Bs[(kt + 1) & 1][wrB[cc]] = make_ushort4(
                        f2bf(((const float*)&bq[0])[cc]), f2bf(((const float*)&bq[1])[cc]),
                        f2bf(((const float*)&bq[2])[cc]), f2bf(((const float*)&bq[3])[cc]));
                int knx = (kt + 2 < NT) ? (kt + 2) * 64 : (NT - 1) * 64;
#pragma unroll
                for (int i = 0; i < 4; ++i)
                    bq[i] = *(const float4*)&W[(size_t)(knx + kq + i) * (2 * F_DIM) + srccol];
            }
            __builtin_amdgcn_sched_barrier(0);
            const unsigned short* A_ = As[s & 1];
            const unsigned short* B_ = Bs[kt & 1];
            const int ks = s & 1;
            short8v bf[4];
#pragma unroll
            for (int fn = 0; fn < 4; ++fn) bf[fn] = *(const short8v*)&B_[rdB[fn][ks]];
#pragma unroll
            for (int fm = 0; fm < 4; ++fm) {
                short8v af = *(const short8v*)&A_[rdA[fm]];
#pragma unroll
                for (int fn = 0; fn < 4; ++fn)
                    acc[fm][fn] = __builtin_amdgcn_mfma_f32_16x16x32_bf16(af, bf[fn], acc[fm][fn], 0, 0, 0);
            }
            __syncthreads();
        }

        // epilogue: pairs (fn0,fn2) p=0 and (fn1,fn3) p=1
#pragma unroll
        for (int fm = 0; fm < 4; ++fm) {
#pragma unroll
            for (int p = 0; p < 2; ++p) {
                const int acol = c0 + wn * 32 + p * 16 + lrow;
#pragma unroll
                for (int i = 0; i < 4; ++i) {
                    int ml = wm * 64 + fm * 16 + lhi * 4 + i;
                    int idx = m0 + ml;
                    if (idx < ne) {
                        float gv = acc[fm][p][i], uv = acc[fm][p + 2][i];
                        float sg = gv / (1.f + __expf(-gv));
                        float val = sg * uv * twsS[ml];
                        size_t orow = ROUTED ? (size_t)(base + idx) : (size_t)idx;
                        actout[orow * F_DIM + acol] = f2bf(val);
                    }
                }
            }
        }
    }
}

// ---------------------------------------------------------------------------
// down-proj — same structure, BN=128 out cols. B tile [128 n][64 k],
// n = out col - c0. Wave covers out cols c0 + wn*64 + fn*16 + lrow.
// ---------------------------------------------------------------------------
template<bool ROUTED>
__global__ __launch_bounds__(512, 4) void down_mfma_kernel(
    const unsigned short* __restrict__ actb,
    const float* __restrict__ Wall,
    const int* __restrict__ counts, const int* __restrict__ offsets,
    const int* __restrict__ bucket_tok, const float* __restrict__ sgate,
    float* __restrict__ out)
{
    constexpr int BM = 256;
    __shared__ __align__(16) unsigned short As[2][BM * 32];
    __shared__ __align__(16) unsigned short Bs[2][128 * 64];
    __shared__ int   toksS[BM];
    __shared__ float sgS[BM];

    const int tid  = threadIdx.x;
    const int lane = tid & 63;
    const int wid  = tid >> 6;
    const int wm = wid >> 1, wn = wid & 1;
    const int lrow = lane & 15, lhi = lane >> 4;

    int cblk, mt, ne, base;
    const float* W;
    if (ROUTED) {
        int nw = (blockIdx.x & 7) * ((int)gridDim.x >> 3) + (blockIdx.x >> 3);
        int e = nw >> 5; mt = (nw >> 4) & 1; cblk = nw & 15;
        ne = counts[e]; base = offsets[e];
        if (mt * BM >= ne) return;
        W = Wall + (size_t)e * F_DIM * H_DIM;
    } else {
        cblk = blockIdx.x; mt = blockIdx.y;
        ne = T_TOK; base = 0;
        W = Wall;
    }
    const int c0 = cblk * 128;

    const int n4 = (tid & 31) * 4;
    const int kq = (tid >> 5) * 4;
    const int srccol = c0 + n4;
    int wrB[4];
#pragma unroll
    for (int cc = 0; cc < 4; ++cc) {
        int n = n4 + cc;
        wrB[cc] = n * 64 + BCHUNK(n, kq >> 3) * 8 + (kq & 7);
    }
    int rdB[4][2];
#pragma unroll
    for (int fn = 0; fn < 4; ++fn) {
        int r = wn * 64 + fn * 16 + lrow;
#pragma unroll
        for (int ks = 0; ks < 2; ++ks) {
            int kc = ks * 4 + lhi;
            rdB[fn][ks] = r * 64 + BCHUNK(r, kc) * 8;
        }
    }
    int rdA[4];
#pragma unroll
    for (int fm = 0; fm < 4; ++fm) {
        int arow = wm * 64 + fm * 16 + lrow;
        rdA[fm] = arow * 32 + ((lhi ^ ASW32(arow)) << 3);
    }
    const int ar0 = wid * 32 + (lane >> 2);
    const int ar1 = ar0 + 16;
    const int NT   = F_DIM / 64;
    const int SMAX = F_DIM / 32;
    const int m0_stride = ROUTED ? (2 * BM) : ((int)gridDim.y * BM);

    for (int m0 = mt * BM; m0 < ne; m0 += m0_stride) {
        __syncthreads();
        if (tid < BM) {
            int idx = m0 + tid;
            if (ROUTED) {
                toksS[tid] = (idx < ne) ? bucket_tok[base + idx] : 0;
            } else {
                sgS[tid] = sgate[(idx < ne) ? idx : (T_TOK - 1)];
            }
        }
        __syncthreads();

        int g0 = ROUTED ? min(base + m0 + ar0, NROWS - 1) : min(m0 + ar0, T_TOK - 1);
        int g1 = ROUTED ? min(base + m0 + ar1, NROWS - 1) : min(m0 + ar1, T_TOK - 1);
        const int src0 = g0 * F_DIM + (((lane & 3) ^ ASW32(ar0)) << 3);
        const int src1 = g1 * F_DIM + (((lane & 3) ^ ASW32(ar1)) << 3);

        f32x4 acc[4][4];
#pragma unroll
        for (int i = 0; i < 4; ++i)
#pragma unroll
            for (int j = 0; j < 4; ++j) acc[i][j] = (f32x4){0.f, 0.f, 0.f, 0.f};

        float4 bq[4];
#pragma unroll
        for (int i = 0; i < 4; ++i)
            bq[i] = *(const float4*)&W[(size_t)(kq + i) * H_DIM + srccol];
        GLDS16(actb + src0, &As[0][(wid * 32) * 32]);
        GLDS16(actb + src1, &As[0][(wid * 32 + 16) * 32]);
#pragma unroll
        for (int cc = 0; cc < 4; ++cc)
            *(ushort4*)&Bs[0][wrB[cc]] = make_ushort4(
                f2bf(((const float*)&bq[0])[cc]), f2bf(((const float*)&bq[1])[cc]),
                f2bf(((const float*)&bq[2])[cc]), f2bf(((const float*)&bq[3])[cc]));
#pragma unroll
        for (int i = 0; i < 4; ++i)
            bq[i] = *(const float4*)&W[(size_t)(64 + kq + i) * H_DIM + srccol];
        __syncthreads();

        for (int s = 0; s < SMAX; ++s) {
            const int kt = s >> 1;
            if (s + 1 < SMAX) {
                const int kof = (s + 1) * 32;
                GLDS16(actb + src0 + kof, &As[(s + 1) & 1][(wid * 32) * 32]);
                GLDS16(actb + src1 + kof, &As[(s + 1) & 1][(wid * 32 + 16) * 32]);
            }
            if ((s & 1) && (kt + 1 < NT)) {
#pragma unroll
                for (int cc = 0; cc < 4; ++cc)
                    *(ushort4*)&Bs[(kt + 1) & 1][wrB[cc]] = make_ushort4(
                        f2bf(((const float*)&bq[0])[cc]), f2bf(((const float*)&bq[1])[cc]),
                        f2bf(((const float*)&bq[2])[cc]), f2bf(((const float*)&bq[3])[cc]));
                int knx = (kt + 2 < NT) ? (kt + 2) * 64 : (NT - 1) * 64;
#pragma unroll
                for (int i = 0; i < 4; ++i)
                    bq[i] = *(const float4*)&W[(size_t)(knx + kq + i) * H_DIM + srccol];
            }
            __builtin_amdgcn_sched_barrier(0);
            const unsigned short* A_ = As[s & 1];
            const unsigned short* B_ = Bs[kt & 1];
            const int ks = s & 1;
            short8v bf[4];
#pragma unroll
            for (int fn = 0; fn < 4; ++fn) bf[fn] = *(const short8v*)&B_[rdB[fn][ks]];
#pragma unroll
            for (int fm = 0; fm < 4; ++fm) {
                short8v af = *(const short8v*)&A_[rdA[fm]];
#pragma unroll
                for (int fn = 0; fn < 4; ++fn)
                    acc[fm][fn] = __builtin_amdgcn_mfma_f32_16x16x32_bf16(af, bf[fn], acc[fm][fn], 0, 0, 0);
            }
            __syncthreads();
        }

#pragma unroll
        for (int fm = 0; fm < 4; ++fm) {
#pragma unroll
            for (int fn = 0; fn < 4; ++fn) {
                int col = c0 + wn * 64 + fn * 16 + lrow;
#pragma unroll
                for (int i = 0; i < 4; ++i) {
                    int ml = wm * 64 + fm * 16 + lhi * 4 + i;
                    int idx = m0 + ml;
                    if (idx < ne) {
                        if (ROUTED) {
                            atomicAdd(&out[(size_t)toksS[ml] * H_DIM + col], acc[fm][fn][i]);
                        } else {
                            out[(size_t)idx * H_DIM + col] = sgS[ml] * acc[fm][fn][i];
                        }
                    }
                }
            }
        }
    }
}

// ---------------------------------------------------------------------------
extern "C" void kernel_launch(void* const* d_in, const int* in_sizes, int n_in,
                              void* d_out, int out_size, void* d_ws, size_t ws_size,
                              hipStream_t stream) {
    const float* x    = (const float*)d_in[0];
    const float* Wg   = (const float*)d_in[1];
    const float* Wgu  = (const float*)d_in[2];
    const float* Wd   = (const float*)d_in[3];
    const float* Wsgu = (const float*)d_in[4];
    const float* Wsd  = (const float*)d_in[5];
    float* out = (float*)d_out;

    char* p = (char*)d_ws;
    auto alloc = [&](size_t bytes) {
        char* r = p;
        p += (bytes + 255) & ~(size_t)255;
        return r;
    };
    int*   topk_idx   = (int*)  alloc((size_t)T_TOK * K_TOP * sizeof(int));
    float* topk_w     = (float*)alloc((size_t)T_TOK * K_TOP * sizeof(float));
    float* sgate      = (float*)alloc((size_t)T_TOK * sizeof(float));
    int*   counts     = (int*)  alloc((size_t)E_NUM * sizeof(int));
    int*   offsets    = (int*)  alloc((size_t)E_NUM * sizeof(int));
    int*   bucket_tok = (int*)  alloc((size_t)NROWS * sizeof(int));
    float* bucket_w   = (float*)alloc((size_t)NROWS * sizeof(float));
    unsigned short* xb    = (unsigned short*)alloc((size_t)T_TOK * H_DIM * sizeof(short));
    unsigned short* act_r = (unsigned short*)alloc((size_t)NROWS * F_DIM * sizeof(short));
    unsigned short* act_s = (unsigned short*)alloc((size_t)T_TOK * FS_DIM * sizeof(short));

    hipMemsetAsync(counts, 0, E_NUM * sizeof(int), stream);
    cvt_bf16_kernel<<<(T_TOK * H_DIM / 8 + 255) / 256, 256, 0, stream>>>(x, xb, T_TOK * H_DIM / 8);
    router_kernel<<<T_TOK, 64, 0, stream>>>(x, Wg, topk_idx, topk_w, sgate, counts);
    bucket_kernel<<<E_NUM, 256, 0, stream>>>(topk_idx, topk_w, counts, offsets, bucket_tok, bucket_w);

    // routed gate_up: 8 colblks x 64 experts x 2 m-tiles (overflow tile exits)
    gu_mfma_kernel<true><<<8 * E_NUM * 2, 512, 0, stream>>>(
        xb, Wgu, counts, offsets, bucket_tok, bucket_w, act_r);
    // shared gate_up: 8 colblks x 8 m-tiles
    gu_mfma_kernel<false><<<dim3(8, T_TOK / 256), 512, 0, stream>>>(
        xb, Wsgu, counts, offsets, bucket_tok, bucket_w, act_s);

    // shared down writes out first; routed down accumulates atomically on top
    down_mfma_kernel<false><<<dim3(16, T_TOK / 256), 512, 0, stream>>>(
        act_s, Wsd, counts, offsets, bucket_tok, sgate, out);
    down_mfma_kernel<true><<<16 * E_NUM * 2, 512, 0, stream>>>(
        act_r, Wd, counts, offsets, bucket_tok, sgate, out);
}